// Round 1
// baseline (1026.585 us; speedup 1.0000x reference)
//
#include <hip/hip_runtime.h>
#include <hip/hip_fp16.h>
#include <math.h>

#define HID 16
#define RANGES 8

// ---------------------------------------------------------------------------
// CSR build: count in-degrees, hierarchical prefix-sum, range-filtered scatter
// ---------------------------------------------------------------------------

// Plain (cached) loads: this pass warms L3 with dst for fill_csr's 8 re-reads.
__global__ void count_deg(const int* __restrict__ dst, int* __restrict__ cnt, int E) {
    int e = blockIdx.x * blockDim.x + threadIdx.x;
    if (e < E) atomicAdd(&cnt[dst[e]], 1);
}

__global__ void block_reduce(const int* __restrict__ cnt, int* __restrict__ bsum, int N) {
    int i = blockIdx.x * blockDim.x + threadIdx.x;
    int v = (i < N) ? cnt[i] : 0;
#pragma unroll
    for (int o = 1; o < 64; o <<= 1) v += __shfl_xor(v, o);
    __shared__ int ws[4];
    int lane = threadIdx.x & 63;
    int wid = threadIdx.x >> 6;
    if (lane == 0) ws[wid] = v;
    __syncthreads();
    if (threadIdx.x == 0) bsum[blockIdx.x] = ws[0] + ws[1] + ws[2] + ws[3];
}

__global__ void scan_bsums(int* __restrict__ bsum, int* __restrict__ row_ptr,
                           int nb, int N) {
    __shared__ int s[1024];
    int t = threadIdx.x;
    int v = (t < nb) ? bsum[t] : 0;
    s[t] = v;
    __syncthreads();
    for (int o = 1; o < 1024; o <<= 1) {
        int add = (t >= o) ? s[t - o] : 0;
        __syncthreads();
        s[t] += add;
        __syncthreads();
    }
    if (t < nb) bsum[t] = s[t] - v;            // exclusive
    if (t == 0) row_ptr[N] = s[1023];          // total == E
}

// Stage 3 + encoder fused: scan cnt -> row_ptr/cursor/w9, compute dinv, and
// immediately run the per-node MLP encoder (dinv is in-register here).
__global__ void finalize_encode(const int* __restrict__ cnt, const int* __restrict__ bsum,
                                int* __restrict__ row_ptr, int* __restrict__ cursor,
                                float* __restrict__ w9, float* __restrict__ dinv,
                                const float* __restrict__ x, const float* __restrict__ W1,
                                const float* __restrict__ b1, const float* __restrict__ W2,
                                const float* __restrict__ b2,
                                float* __restrict__ g0f, __half* __restrict__ gh0, int N) {
    __shared__ int s[256];
    int t = threadIdx.x;
    int i = blockIdx.x * blockDim.x + t;
    int c = (i < N) ? cnt[i] : 0;
    s[t] = c;
    __syncthreads();
    for (int o = 1; o < 256; o <<= 1) {
        int add = (t >= o) ? s[t - o] : 0;
        __syncthreads();
        s[t] += add;
        __syncthreads();
    }
    if (i >= N) return;
    int off = bsum[blockIdx.x] + s[t] - c;
    row_ptr[i] = off;
    cursor[i]  = off;
    float deg = (float)(c + 1);                 // +1 self-loop
    w9[i]   = 0.9f / deg;
    float dv = rsqrtf(deg);
    dinv[i] = dv;

    // ---- encoder: g0 = dinv * relu(relu(x*W1+b1)@W2+b2) ----
    float xv = x[i];
    float h1[HID];
#pragma unroll
    for (int j = 0; j < HID; ++j) h1[j] = fmaxf(xv * W1[j] + b1[j], 0.0f);
#pragma unroll
    for (int j = 0; j < HID; ++j) {
        float acc = b2[j];
#pragma unroll
        for (int q = 0; q < HID; ++q) acc += h1[q] * W2[q * HID + j];
        float g = dv * fmaxf(acc, 0.0f);
        g0f[i * HID + j] = g;
        gh0[i * HID + j] = __float2half(g);
    }
}

// Range-filtered scatter: blockIdx%8 selects a dst range; round-robin
// workgroup->XCD dispatch keeps each col window mostly in one XCD's L2.
// Cached (non-NT) loads: dst/src stay L3-resident across the 8 passes.
__global__ void fill_csr(const int* __restrict__ src, const int* __restrict__ dst,
                         int* __restrict__ cursor, int* __restrict__ col,
                         int E, int range_step, int N) {
    int r = blockIdx.x & (RANGES - 1);
    int chunk = blockIdx.x >> 3;
    int nchunks = gridDim.x >> 3;
    int lo = r * range_step;
    int hi = min(lo + range_step, N);
    int stride = nchunks * blockDim.x;
    for (int e = chunk * blockDim.x + threadIdx.x; e < E; e += stride) {
        int d = dst[e];
        if (d >= lo && d < hi) {
            int sv = src[e];
            int p = atomicAdd(&cursor[d], 1);
            col[p] = sv;
        }
    }
}

// ---------------------------------------------------------------------------
// One APPNP round: g_out[v] = w9[v]*(sum_in g_in[src] + g_in[v]) + 0.1*g0[v]
// g state fp16 (3.2MB, L2-resident); accumulate fp32 via v_fma_mix_f32.
// 4 lanes/node: each lane owns 4 h-elements (8B uint2 slice of the 32B row).
// ds_swizzle broadcasts col entries within the 4-lane group (1 instr, no
// lane-address math); per-edge cost ~0.39 wave-instrs vs ~1.1 before.
// ---------------------------------------------------------------------------

// acc += (float)f16(lo/hi half of h): one VOP3P instruction per element.
#define FMA_MIX_LO(a, h) \
    asm("v_fma_mix_f32 %0, %1, %2, %0 op_sel:[0,0,0] op_sel_hi:[1,0,0]" \
        : "+v"(a) : "v"(h), "v"(one))
#define FMA_MIX_HI(a, h) \
    asm("v_fma_mix_f32 %0, %1, %2, %0 op_sel:[1,0,0] op_sel_hi:[1,0,0]" \
        : "+v"(a) : "v"(h), "v"(one))

__device__ __forceinline__ void acc_edge(const uint2* __restrict__ gb, int c, int j4,
                                         float& a0, float& a1, float& a2, float& a3,
                                         float one) {
    uint2 hv = gb[(size_t)c * 4 + j4];   // 8B slice: halves j4*4 .. j4*4+3
    FMA_MIX_LO(a0, hv.x);
    FMA_MIX_HI(a1, hv.x);
    FMA_MIX_LO(a2, hv.y);
    FMA_MIX_HI(a3, hv.y);
}

// Broadcast each of the 4 col entries held across the 4-lane group.
// ds_swizzle BitMode: lane' = (lane & 0x1C) | i  ->  offset = (i<<5)|0x1C.
#define ACC4(cv) \
    acc_edge(gb, __builtin_amdgcn_ds_swizzle((cv), 0x1C), j4, a0, a1, a2, a3, one); \
    acc_edge(gb, __builtin_amdgcn_ds_swizzle((cv), 0x3C), j4, a0, a1, a2, a3, one); \
    acc_edge(gb, __builtin_amdgcn_ds_swizzle((cv), 0x5C), j4, a0, a1, a2, a3, one); \
    acc_edge(gb, __builtin_amdgcn_ds_swizzle((cv), 0x7C), j4, a0, a1, a2, a3, one);

__device__ __forceinline__ void gather_accum(const __half* __restrict__ gin,
                                             const int* __restrict__ col,
                                             int v, int s, int e, int j4,
                                             float& a0, float& a1, float& a2, float& a3) {
    const uint2* gb = (const uint2*)gin;
    const float one = 1.0f;
    a0 = a1 = a2 = a3 = 0.0f;
    acc_edge(gb, v, j4, a0, a1, a2, a3, one);   // self-loop term

    int k = s;
    for (; k + 16 <= e; k += 16) {
        int cv0 = __builtin_nontemporal_load(col + k + j4);
        int cv1 = __builtin_nontemporal_load(col + k + 4 + j4);
        int cv2 = __builtin_nontemporal_load(col + k + 8 + j4);
        int cv3 = __builtin_nontemporal_load(col + k + 12 + j4);
        ACC4(cv0);
        ACC4(cv1);
        ACC4(cv2);
        ACC4(cv3);
    }
    for (; k + 4 <= e; k += 4) {
        int cv = __builtin_nontemporal_load(col + k + j4);
        ACC4(cv);
    }
    int rem = e - k;   // 0..3
    if (rem) {
        int cv = (j4 < rem) ? __builtin_nontemporal_load(col + k + j4) : 0;
        acc_edge(gb, __builtin_amdgcn_ds_swizzle(cv, 0x1C), j4, a0, a1, a2, a3, one);
        if (rem > 1) acc_edge(gb, __builtin_amdgcn_ds_swizzle(cv, 0x3C), j4, a0, a1, a2, a3, one);
        if (rem > 2) acc_edge(gb, __builtin_amdgcn_ds_swizzle(cv, 0x5C), j4, a0, a1, a2, a3, one);
    }
}

__global__ void prop(const __half* __restrict__ gin, const float* __restrict__ g0f,
                     const int* __restrict__ row_ptr, const int* __restrict__ col,
                     const float* __restrict__ w9, __half* __restrict__ gout, int N) {
    int gid = blockIdx.x * blockDim.x + threadIdx.x;
    int v = gid >> 2;
    if (v >= N) return;
    int j4 = threadIdx.x & 3;

    int s = row_ptr[v];
    int e = row_ptr[v + 1];

    float a0, a1, a2, a3;
    gather_accum(gin, col, v, s, e, j4, a0, a1, a2, a3);

    float wv = w9[v];
    float4 g0 = *reinterpret_cast<const float4*>(g0f + (size_t)v * HID + j4 * 4);
    union { __half2 h2[2]; uint2 u; } pk;
    pk.h2[0] = __floats2half2_rn(wv * a0 + 0.1f * g0.x, wv * a1 + 0.1f * g0.y);
    pk.h2[1] = __floats2half2_rn(wv * a2 + 0.1f * g0.z, wv * a3 + 0.1f * g0.w);
    *reinterpret_cast<uint2*>(gout + (size_t)v * HID + j4 * 4) = pk.u;
}

// Final round fused with the head: compute g_final in registers, reduce
// g_final . W3 across the 4-lane group, write y directly (no gout write).
__global__ void prop_last(const __half* __restrict__ gin, const float* __restrict__ g0f,
                          const int* __restrict__ row_ptr, const int* __restrict__ col,
                          const float* __restrict__ w9, const float* __restrict__ dinv,
                          const float* __restrict__ W3, const float* __restrict__ b3,
                          float* __restrict__ y, int N) {
    int gid = blockIdx.x * blockDim.x + threadIdx.x;
    int v = gid >> 2;
    if (v >= N) return;
    int j4 = threadIdx.x & 3;

    int s = row_ptr[v];
    int e = row_ptr[v + 1];

    float a0, a1, a2, a3;
    gather_accum(gin, col, v, s, e, j4, a0, a1, a2, a3);

    float wv = w9[v];
    float4 g0 = *reinterpret_cast<const float4*>(g0f + (size_t)v * HID + j4 * 4);
    float gf0 = wv * a0 + 0.1f * g0.x;
    float gf1 = wv * a1 + 0.1f * g0.y;
    float gf2 = wv * a2 + 0.1f * g0.z;
    float gf3 = wv * a3 + 0.1f * g0.w;

    float4 w3 = *reinterpret_cast<const float4*>(W3 + j4 * 4);
    float t = gf0 * w3.x + gf1 * w3.y + gf2 * w3.z + gf3 * w3.w;
    t += __shfl_xor(t, 1, 4);
    t += __shfl_xor(t, 2, 4);
    if (j4 == 0) y[v] = t / dinv[v] + b3[0];
}

extern "C" void kernel_launch(void* const* d_in, const int* in_sizes, int n_in,
                              void* d_out, int out_size, void* d_ws, size_t ws_size,
                              hipStream_t stream) {
    const float* x  = (const float*)d_in[0];
    const int* edge = (const int*)d_in[1];
    const float* W1 = (const float*)d_in[2];
    const float* b1 = (const float*)d_in[3];
    const float* W2 = (const float*)d_in[4];
    const float* b2 = (const float*)d_in[5];
    const float* W3 = (const float*)d_in[6];
    const float* b3 = (const float*)d_in[7];
    float* y = (float*)d_out;

    const int N = in_sizes[0];       // 100000
    const int E = in_sizes[1] / 2;   // 5000000
    const int* src = edge;
    const int* dst = edge + E;

    char* ws = (char*)d_ws;
    size_t off = 0;
    auto alloc = [&](size_t bytes) -> void* {
        void* p = ws + off;
        off += (bytes + 255) & ~(size_t)255;
        return p;
    };

    int*    cnt     = (int*)   alloc((size_t)N * 4);
    int*    row_ptr = (int*)   alloc((size_t)(N + 1) * 4);
    int*    cursor  = (int*)   alloc((size_t)N * 4);
    int*    col     = (int*)   alloc((size_t)E * 4);
    float*  w9      = (float*) alloc((size_t)N * 4);
    float*  dinv    = (float*) alloc((size_t)N * 4);
    float*  g0f     = (float*) alloc((size_t)N * HID * 4);
    __half* gA      = (__half*)alloc((size_t)N * HID * 2);
    __half* gB      = (__half*)alloc((size_t)N * HID * 2);
    int*    bsum    = (int*)   alloc(1024 * 4);

    const int nb = (N + 255) / 256;   // 391 <= 1024

    hipMemsetAsync(cnt, 0, (size_t)N * 4, stream);

    count_deg<<<(E + 255) / 256, 256, 0, stream>>>(dst, cnt, E);
    block_reduce<<<nb, 256, 0, stream>>>(cnt, bsum, N);
    scan_bsums<<<1, 1024, 0, stream>>>(bsum, row_ptr, nb, N);
    finalize_encode<<<nb, 256, 0, stream>>>(cnt, bsum, row_ptr, cursor, w9, dinv,
                                            x, W1, b1, W2, b2, g0f, gA, N);

    int range_step = (N + RANGES - 1) / RANGES;
    fill_csr<<<2048, 256, 0, stream>>>(src, dst, cursor, col, E, range_step, N);

    const __half* gin = gA;
    __half* gout = gB;
    long long total = (long long)N * 4;        // 4 lanes per node
    int pgrid = (int)((total + 255) / 256);
    for (int k = 0; k < 9; ++k) {
        prop<<<pgrid, 256, 0, stream>>>(gin, g0f, row_ptr, col, w9, gout, N);
        const __half* t = gin; gin = gout; gout = (__half*)t;
    }
    prop_last<<<pgrid, 256, 0, stream>>>(gin, g0f, row_ptr, col, w9, dinv, W3, b3, y, N);
}

// Round 2
// 920.589 us; speedup vs baseline: 1.1151x; 1.1151x over previous
//
#include <hip/hip_runtime.h>
#include <hip/hip_fp16.h>
#include <math.h>

#define HID 16
#define RANGES 8

// ---------------------------------------------------------------------------
// CSR build: count in-degrees, hierarchical prefix-sum, range-filtered scatter
// ---------------------------------------------------------------------------

// Plain (cached) loads: this pass warms L3 with dst for fill_csr's 8 re-reads.
__global__ void count_deg(const int* __restrict__ dst, int* __restrict__ cnt, int E) {
    int e = blockIdx.x * blockDim.x + threadIdx.x;
    if (e < E) atomicAdd(&cnt[dst[e]], 1);
}

__global__ void block_reduce(const int* __restrict__ cnt, int* __restrict__ bsum, int N) {
    int i = blockIdx.x * blockDim.x + threadIdx.x;
    int v = (i < N) ? cnt[i] : 0;
#pragma unroll
    for (int o = 1; o < 64; o <<= 1) v += __shfl_xor(v, o);
    __shared__ int ws[4];
    int lane = threadIdx.x & 63;
    int wid = threadIdx.x >> 6;
    if (lane == 0) ws[wid] = v;
    __syncthreads();
    if (threadIdx.x == 0) bsum[blockIdx.x] = ws[0] + ws[1] + ws[2] + ws[3];
}

__global__ void scan_bsums(int* __restrict__ bsum, int* __restrict__ row_ptr,
                           int nb, int N) {
    __shared__ int s[1024];
    int t = threadIdx.x;
    int v = (t < nb) ? bsum[t] : 0;
    s[t] = v;
    __syncthreads();
    for (int o = 1; o < 1024; o <<= 1) {
        int add = (t >= o) ? s[t - o] : 0;
        __syncthreads();
        s[t] += add;
        __syncthreads();
    }
    if (t < nb) bsum[t] = s[t] - v;            // exclusive
    if (t == 0) row_ptr[N] = s[1023];          // total == E
}

// Stage 3 + encoder fused: scan cnt -> row_ptr/cursor/w9, compute dinv, and
// immediately run the per-node MLP encoder + head projection.
// KEY: y = h_K @ W3 + b3 is scalar per node and propagation is linear, so we
// project h0 @ W3 BEFORE propagating: z0 = dinv * (relu-MLP(x) @ W3).
// The APPNP recurrence on z is identical in form (HID=1).
__global__ void finalize_encode(const int* __restrict__ cnt, const int* __restrict__ bsum,
                                int* __restrict__ row_ptr, int* __restrict__ cursor,
                                float* __restrict__ w9, float* __restrict__ dinv,
                                const float* __restrict__ x, const float* __restrict__ W1,
                                const float* __restrict__ b1, const float* __restrict__ W2,
                                const float* __restrict__ b2, const float* __restrict__ W3,
                                float* __restrict__ z0, int N) {
    __shared__ int s[256];
    int t = threadIdx.x;
    int i = blockIdx.x * blockDim.x + t;
    int c = (i < N) ? cnt[i] : 0;
    s[t] = c;
    __syncthreads();
    for (int o = 1; o < 256; o <<= 1) {
        int add = (t >= o) ? s[t - o] : 0;
        __syncthreads();
        s[t] += add;
        __syncthreads();
    }
    if (i >= N) return;
    int off = bsum[blockIdx.x] + s[t] - c;
    row_ptr[i] = off;
    cursor[i]  = off;
    float deg = (float)(c + 1);                 // +1 self-loop
    w9[i]   = 0.9f / deg;
    float dv = rsqrtf(deg);
    dinv[i] = dv;

    // ---- encoder + head: z0 = dinv * (relu(relu(x*W1+b1)@W2+b2) @ W3) ----
    float xv = x[i];
    float h1[HID];
#pragma unroll
    for (int j = 0; j < HID; ++j) h1[j] = fmaxf(xv * W1[j] + b1[j], 0.0f);
    float zacc = 0.0f;
#pragma unroll
    for (int j = 0; j < HID; ++j) {
        float acc = b2[j];
#pragma unroll
        for (int q = 0; q < HID; ++q) acc += h1[q] * W2[q * HID + j];
        zacc += fmaxf(acc, 0.0f) * W3[j];
    }
    z0[i] = dv * zacc;
}

// Range-filtered scatter: blockIdx%8 selects a dst range; round-robin
// workgroup->XCD dispatch keeps each col window mostly in one XCD's L2.
// Cached (non-NT) loads: dst/src stay L3-resident across the 8 passes.
__global__ void fill_csr(const int* __restrict__ src, const int* __restrict__ dst,
                         int* __restrict__ cursor, int* __restrict__ col,
                         int E, int range_step, int N) {
    int r = blockIdx.x & (RANGES - 1);
    int chunk = blockIdx.x >> 3;
    int nchunks = gridDim.x >> 3;
    int lo = r * range_step;
    int hi = min(lo + range_step, N);
    int stride = nchunks * blockDim.x;
    for (int e = chunk * blockDim.x + threadIdx.x; e < E; e += stride) {
        int d = dst[e];
        if (d >= lo && d < hi) {
            int sv = src[e];
            int p = atomicAdd(&cursor[d], 1);
            col[p] = sv;
        }
    }
}

// ---------------------------------------------------------------------------
// Scalar APPNP round: z_out[v] = w9[v]*(sum_in z[src] + z[v]) + 0.1*z0[v]
// z state fp32, 400KB -> L2-resident on every XCD with ~50x line reuse.
// 4 lanes/node, each strides its row by 4; col stream stays NT (single-use);
// 2-deep accumulator unroll for gather ILP; shfl-reduce over the 4-lane group.
// ---------------------------------------------------------------------------
__device__ __forceinline__ float row_sum(const float* __restrict__ zin,
                                         const int* __restrict__ col,
                                         int s, int e, int j) {
    float acc = 0.0f, acc2 = 0.0f;
    int k = s + j;
    for (; k + 4 < e; k += 8) {
        int c0 = __builtin_nontemporal_load(col + k);
        int c1 = __builtin_nontemporal_load(col + k + 4);
        acc  += zin[c0];
        acc2 += zin[c1];
    }
    if (k < e) acc += zin[__builtin_nontemporal_load(col + k)];
    acc += acc2;
    acc += __shfl_xor(acc, 1, 4);
    acc += __shfl_xor(acc, 2, 4);
    return acc;
}

__global__ void prop_scalar(const float* __restrict__ zin, const float* __restrict__ z0,
                            const int* __restrict__ row_ptr, const int* __restrict__ col,
                            const float* __restrict__ w9, float* __restrict__ zout, int N) {
    int gid = blockIdx.x * blockDim.x + threadIdx.x;
    int v = gid >> 2;
    if (v >= N) return;
    int j = threadIdx.x & 3;
    int s = row_ptr[v];
    int e = row_ptr[v + 1];
    float acc = row_sum(zin, col, s, e, j);
    if (j == 0) zout[v] = w9[v] * (acc + zin[v]) + 0.1f * z0[v];
}

// Final round fused with the head recovery: y = z_final / dinv + b3.
__global__ void prop_last(const float* __restrict__ zin, const float* __restrict__ z0,
                          const int* __restrict__ row_ptr, const int* __restrict__ col,
                          const float* __restrict__ w9, const float* __restrict__ dinv,
                          const float* __restrict__ b3, float* __restrict__ y, int N) {
    int gid = blockIdx.x * blockDim.x + threadIdx.x;
    int v = gid >> 2;
    if (v >= N) return;
    int j = threadIdx.x & 3;
    int s = row_ptr[v];
    int e = row_ptr[v + 1];
    float acc = row_sum(zin, col, s, e, j);
    if (j == 0) {
        float zf = w9[v] * (acc + zin[v]) + 0.1f * z0[v];
        y[v] = zf / dinv[v] + b3[0];
    }
}

extern "C" void kernel_launch(void* const* d_in, const int* in_sizes, int n_in,
                              void* d_out, int out_size, void* d_ws, size_t ws_size,
                              hipStream_t stream) {
    const float* x  = (const float*)d_in[0];
    const int* edge = (const int*)d_in[1];
    const float* W1 = (const float*)d_in[2];
    const float* b1 = (const float*)d_in[3];
    const float* W2 = (const float*)d_in[4];
    const float* b2 = (const float*)d_in[5];
    const float* W3 = (const float*)d_in[6];
    const float* b3 = (const float*)d_in[7];
    float* y = (float*)d_out;

    const int N = in_sizes[0];       // 100000
    const int E = in_sizes[1] / 2;   // 5000000
    const int* src = edge;
    const int* dst = edge + E;

    char* ws = (char*)d_ws;
    size_t off = 0;
    auto alloc = [&](size_t bytes) -> void* {
        void* p = ws + off;
        off += (bytes + 255) & ~(size_t)255;
        return p;
    };

    int*    cnt     = (int*)   alloc((size_t)N * 4);
    int*    row_ptr = (int*)   alloc((size_t)(N + 1) * 4);
    int*    cursor  = (int*)   alloc((size_t)N * 4);
    int*    col     = (int*)   alloc((size_t)E * 4);
    float*  w9      = (float*) alloc((size_t)N * 4);
    float*  dinv    = (float*) alloc((size_t)N * 4);
    float*  z0f     = (float*) alloc((size_t)N * 4);
    float*  zA      = (float*) alloc((size_t)N * 4);
    float*  zB      = (float*) alloc((size_t)N * 4);
    int*    bsum    = (int*)   alloc(1024 * 4);

    const int nb = (N + 255) / 256;   // 391 <= 1024

    hipMemsetAsync(cnt, 0, (size_t)N * 4, stream);

    count_deg<<<(E + 255) / 256, 256, 0, stream>>>(dst, cnt, E);
    block_reduce<<<nb, 256, 0, stream>>>(cnt, bsum, N);
    scan_bsums<<<1, 1024, 0, stream>>>(bsum, row_ptr, nb, N);
    finalize_encode<<<nb, 256, 0, stream>>>(cnt, bsum, row_ptr, cursor, w9, dinv,
                                            x, W1, b1, W2, b2, W3, z0f, N);

    int range_step = (N + RANGES - 1) / RANGES;
    fill_csr<<<2048, 256, 0, stream>>>(src, dst, cursor, col, E, range_step, N);

    const float* zin = z0f;           // round 0 state IS z0
    float* zout = zA;
    long long total = (long long)N * 4;        // 4 lanes per node
    int pgrid = (int)((total + 255) / 256);
    for (int k = 0; k < 9; ++k) {
        prop_scalar<<<pgrid, 256, 0, stream>>>(zin, z0f, row_ptr, col, w9, zout, N);
        zin = zout;
        zout = (zout == zA) ? zB : zA;
    }
    prop_last<<<pgrid, 256, 0, stream>>>(zin, z0f, row_ptr, col, w9, dinv, b3, y, N);
}

// Round 4
// 901.253 us; speedup vs baseline: 1.1391x; 1.0215x over previous
//
#include <hip/hip_runtime.h>
#include <hip/hip_fp16.h>
#include <math.h>

#define HID 16
#define RANGES 8

typedef int int4v __attribute__((ext_vector_type(4)));   // clang vector: OK for NT builtins

// ---------------------------------------------------------------------------
// CSR build: count in-degrees, hierarchical prefix-sum, range-filtered scatter
// ---------------------------------------------------------------------------

// int4-vectorized degree count: 4 edges/thread/iter, atomics to L2-resident cnt.
__global__ void count_deg(const int* __restrict__ dst, int* __restrict__ cnt, int E) {
    int E4 = E >> 2;
    int t = blockIdx.x * blockDim.x + threadIdx.x;
    int stride = gridDim.x * blockDim.x;
    const int4v* dst4 = (const int4v*)dst;
    for (int q = t; q < E4; q += stride) {
        int4v d = __builtin_nontemporal_load(dst4 + q);
        atomicAdd(&cnt[d.x], 1);
        atomicAdd(&cnt[d.y], 1);
        atomicAdd(&cnt[d.z], 1);
        atomicAdd(&cnt[d.w], 1);
    }
    for (int e = (E4 << 2) + t; e < E; e += stride) atomicAdd(&cnt[dst[e]], 1);
}

__global__ void block_reduce(const int* __restrict__ cnt, int* __restrict__ bsum, int N) {
    int i = blockIdx.x * blockDim.x + threadIdx.x;
    int v = (i < N) ? cnt[i] : 0;
#pragma unroll
    for (int o = 1; o < 64; o <<= 1) v += __shfl_xor(v, o);
    __shared__ int ws[4];
    int lane = threadIdx.x & 63;
    int wid = threadIdx.x >> 6;
    if (lane == 0) ws[wid] = v;
    __syncthreads();
    if (threadIdx.x == 0) bsum[blockIdx.x] = ws[0] + ws[1] + ws[2] + ws[3];
}

__global__ void scan_bsums(int* __restrict__ bsum, int* __restrict__ row_ptr,
                           int nb, int N) {
    __shared__ int s[1024];
    int t = threadIdx.x;
    int v = (t < nb) ? bsum[t] : 0;
    s[t] = v;
    __syncthreads();
    for (int o = 1; o < 1024; o <<= 1) {
        int add = (t >= o) ? s[t - o] : 0;
        __syncthreads();
        s[t] += add;
        __syncthreads();
    }
    if (t < nb) bsum[t] = s[t] - v;            // exclusive
    if (t == 0) row_ptr[N] = s[1023];          // total == E
}

// Stage 3 + encoder fused: scan cnt -> row_ptr/cursor/w9, compute dinv, and
// immediately run the per-node MLP encoder + head projection.
// KEY: y = h_K @ W3 + b3 is scalar per node and propagation is linear, so we
// project h0 @ W3 BEFORE propagating: z0 = dinv * (relu-MLP(x) @ W3).
// The APPNP recurrence on z is identical in form (HID=1).
__global__ void finalize_encode(const int* __restrict__ cnt, const int* __restrict__ bsum,
                                int* __restrict__ row_ptr, int* __restrict__ cursor,
                                float* __restrict__ w9, float* __restrict__ dinv,
                                const float* __restrict__ x, const float* __restrict__ W1,
                                const float* __restrict__ b1, const float* __restrict__ W2,
                                const float* __restrict__ b2, const float* __restrict__ W3,
                                float* __restrict__ z0, int N) {
    __shared__ int s[256];
    int t = threadIdx.x;
    int i = blockIdx.x * blockDim.x + t;
    int c = (i < N) ? cnt[i] : 0;
    s[t] = c;
    __syncthreads();
    for (int o = 1; o < 256; o <<= 1) {
        int add = (t >= o) ? s[t - o] : 0;
        __syncthreads();
        s[t] += add;
        __syncthreads();
    }
    if (i >= N) return;
    int off = bsum[blockIdx.x] + s[t] - c;
    row_ptr[i] = off;
    cursor[i]  = off;
    float deg = (float)(c + 1);                 // +1 self-loop
    w9[i]   = 0.9f / deg;
    float dv = rsqrtf(deg);
    dinv[i] = dv;

    // ---- encoder + head: z0 = dinv * (relu(relu(x*W1+b1)@W2+b2) @ W3) ----
    float xv = x[i];
    float h1[HID];
#pragma unroll
    for (int j = 0; j < HID; ++j) h1[j] = fmaxf(xv * W1[j] + b1[j], 0.0f);
    float zacc = 0.0f;
#pragma unroll
    for (int j = 0; j < HID; ++j) {
        float acc = b2[j];
#pragma unroll
        for (int q = 0; q < HID; ++q) acc += h1[q] * W2[q * HID + j];
        zacc += fmaxf(acc, 0.0f) * W3[j];
    }
    z0[i] = dv * zacc;
}

// Range-filtered scatter: blockIdx%8 selects a dst range; round-robin
// workgroup->XCD dispatch keeps each col window in one XCD's L2.
// dst/src loads are NONTEMPORAL: streaming them through L2 was evicting the
// partially-filled col lines (WRITE_SIZE showed 13x write amplification,
// 263MB for a 20MB col array). NT keeps the 2.5MB col window L2-resident so
// the 16 scattered 4B writes per line combine before one writeback.
__global__ void fill_csr(const int* __restrict__ src, const int* __restrict__ dst,
                         int* __restrict__ cursor, int* __restrict__ col,
                         int E, int range_step, int N) {
    int r = blockIdx.x & (RANGES - 1);
    int chunk = blockIdx.x >> 3;
    int nchunks = gridDim.x >> 3;
    int lo = r * range_step;
    int hi = min(lo + range_step, N);
    int stride = nchunks * blockDim.x;
    int E4 = E >> 2;
    const int4v* dst4 = (const int4v*)dst;
    for (int q = chunk * blockDim.x + threadIdx.x; q < E4; q += stride) {
        int4v d = __builtin_nontemporal_load(dst4 + q);
        int e = q << 2;
        if (d.x >= lo && d.x < hi) {
            int sv = __builtin_nontemporal_load(src + e);
            col[atomicAdd(&cursor[d.x], 1)] = sv;
        }
        if (d.y >= lo && d.y < hi) {
            int sv = __builtin_nontemporal_load(src + e + 1);
            col[atomicAdd(&cursor[d.y], 1)] = sv;
        }
        if (d.z >= lo && d.z < hi) {
            int sv = __builtin_nontemporal_load(src + e + 2);
            col[atomicAdd(&cursor[d.z], 1)] = sv;
        }
        if (d.w >= lo && d.w < hi) {
            int sv = __builtin_nontemporal_load(src + e + 3);
            col[atomicAdd(&cursor[d.w], 1)] = sv;
        }
    }
    for (int e = (E4 << 2) + chunk * blockDim.x + threadIdx.x; e < E; e += stride) {
        int d = __builtin_nontemporal_load(dst + e);
        if (d >= lo && d < hi) {
            int sv = __builtin_nontemporal_load(src + e);
            col[atomicAdd(&cursor[d], 1)] = sv;
        }
    }
}

// ---------------------------------------------------------------------------
// Scalar APPNP round: z_out[v] = w9[v]*(sum_in z[src] + z[v]) + 0.1*z0[v]
// z state fp32, 400KB -> L2-resident on every XCD with ~50x line reuse.
// 4 lanes/node, each strides its row by 4; col stream stays NT (single-use);
// 2-deep accumulator unroll for gather ILP; shfl-reduce over the 4-lane group.
// ---------------------------------------------------------------------------
__device__ __forceinline__ float row_sum(const float* __restrict__ zin,
                                         const int* __restrict__ col,
                                         int s, int e, int j) {
    float acc = 0.0f, acc2 = 0.0f;
    int k = s + j;
    for (; k + 4 < e; k += 8) {
        int c0 = __builtin_nontemporal_load(col + k);
        int c1 = __builtin_nontemporal_load(col + k + 4);
        acc  += zin[c0];
        acc2 += zin[c1];
    }
    if (k < e) acc += zin[__builtin_nontemporal_load(col + k)];
    acc += acc2;
    acc += __shfl_xor(acc, 1, 4);
    acc += __shfl_xor(acc, 2, 4);
    return acc;
}

__global__ void prop_scalar(const float* __restrict__ zin, const float* __restrict__ z0,
                            const int* __restrict__ row_ptr, const int* __restrict__ col,
                            const float* __restrict__ w9, float* __restrict__ zout, int N) {
    int gid = blockIdx.x * blockDim.x + threadIdx.x;
    int v = gid >> 2;
    if (v >= N) return;
    int j = threadIdx.x & 3;
    int s = row_ptr[v];
    int e = row_ptr[v + 1];
    float acc = row_sum(zin, col, s, e, j);
    if (j == 0) zout[v] = w9[v] * (acc + zin[v]) + 0.1f * z0[v];
}

// Final round fused with the head recovery: y = z_final / dinv + b3.
__global__ void prop_last(const float* __restrict__ zin, const float* __restrict__ z0,
                          const int* __restrict__ row_ptr, const int* __restrict__ col,
                          const float* __restrict__ w9, const float* __restrict__ dinv,
                          const float* __restrict__ b3, float* __restrict__ y, int N) {
    int gid = blockIdx.x * blockDim.x + threadIdx.x;
    int v = gid >> 2;
    if (v >= N) return;
    int j = threadIdx.x & 3;
    int s = row_ptr[v];
    int e = row_ptr[v + 1];
    float acc = row_sum(zin, col, s, e, j);
    if (j == 0) {
        float zf = w9[v] * (acc + zin[v]) + 0.1f * z0[v];
        y[v] = zf / dinv[v] + b3[0];
    }
}

extern "C" void kernel_launch(void* const* d_in, const int* in_sizes, int n_in,
                              void* d_out, int out_size, void* d_ws, size_t ws_size,
                              hipStream_t stream) {
    const float* x  = (const float*)d_in[0];
    const int* edge = (const int*)d_in[1];
    const float* W1 = (const float*)d_in[2];
    const float* b1 = (const float*)d_in[3];
    const float* W2 = (const float*)d_in[4];
    const float* b2 = (const float*)d_in[5];
    const float* W3 = (const float*)d_in[6];
    const float* b3 = (const float*)d_in[7];
    float* y = (float*)d_out;

    const int N = in_sizes[0];       // 100000
    const int E = in_sizes[1] / 2;   // 5000000
    const int* src = edge;
    const int* dst = edge + E;

    char* ws = (char*)d_ws;
    size_t off = 0;
    auto alloc = [&](size_t bytes) -> void* {
        void* p = ws + off;
        off += (bytes + 255) & ~(size_t)255;
        return p;
    };

    int*    cnt     = (int*)   alloc((size_t)N * 4);
    int*    row_ptr = (int*)   alloc((size_t)(N + 1) * 4);
    int*    cursor  = (int*)   alloc((size_t)N * 4);
    int*    col     = (int*)   alloc((size_t)E * 4);
    float*  w9      = (float*) alloc((size_t)N * 4);
    float*  dinv    = (float*) alloc((size_t)N * 4);
    float*  z0f     = (float*) alloc((size_t)N * 4);
    float*  zA      = (float*) alloc((size_t)N * 4);
    float*  zB      = (float*) alloc((size_t)N * 4);
    int*    bsum    = (int*)   alloc(1024 * 4);

    const int nb = (N + 255) / 256;   // 391 <= 1024

    hipMemsetAsync(cnt, 0, (size_t)N * 4, stream);

    count_deg<<<2048, 256, 0, stream>>>(dst, cnt, E);
    block_reduce<<<nb, 256, 0, stream>>>(cnt, bsum, N);
    scan_bsums<<<1, 1024, 0, stream>>>(bsum, row_ptr, nb, N);
    finalize_encode<<<nb, 256, 0, stream>>>(cnt, bsum, row_ptr, cursor, w9, dinv,
                                            x, W1, b1, W2, b2, W3, z0f, N);

    int range_step = (N + RANGES - 1) / RANGES;
    fill_csr<<<2048, 256, 0, stream>>>(src, dst, cursor, col, E, range_step, N);

    const float* zin = z0f;           // round 0 state IS z0
    float* zout = zA;
    long long total = (long long)N * 4;        // 4 lanes per node
    int pgrid = (int)((total + 255) / 256);
    for (int k = 0; k < 9; ++k) {
        prop_scalar<<<pgrid, 256, 0, stream>>>(zin, z0f, row_ptr, col, w9, zout, N);
        zin = zout;
        zout = (zout == zA) ? zB : zA;
    }
    prop_last<<<pgrid, 256, 0, stream>>>(zin, z0f, row_ptr, col, w9, dinv, b3, y, N);
}